// Round 12
// baseline (8106.615 us; speedup 1.0000x reference)
//
#include <hip/hip_runtime.h>
#include <math.h>

#define DEV __device__ __forceinline__

DEV float sigmoid_(float x) { return 1.0f / (1.0f + __expf(-x)); }
DEV float tanh_(float x) {
    float e = __expf(2.0f * x);
    return 1.0f - 2.0f / (e + 1.0f);
}

// ---------------------------------------------------------------------------
// zx_k (scalar-weight; only for L0 where Cin==1): z_x = bias + conv3x3(x_t).
// zx layout: [B,TcMax,4,hid,H,W]
// ---------------------------------------------------------------------------
template<int TPB, int OCL, int RPT>
__global__ __launch_bounds__(TPB) void zx_k(
    const float* __restrict__ xin, const float* __restrict__ w,
    const float* __restrict__ bias, float* __restrict__ zx,
    int t0, int TcAct, int TcMax, int B, int T, int Cin, int Ctot,
    int hid, int H, int W, int nOcg, int BPP)
{
    const int HW = H * W;
    int blk   = blockIdx.x;
    int chunk = blk % BPP;
    int ocg   = (blk / BPP) % nOcg;
    int tc    = (blk / (BPP * nOcg)) % TcAct;
    int b     = blk / (BPP * nOcg * TcAct);
    int oc0   = ocg * OCL;

    int p    = threadIdx.x;
    int col  = p % W;
    int rowg = p / W;
    int rpc  = (TPB / W) * RPT;
    int y0   = chunk * rpc + rowg * RPT;

    int   off[RPT + 2][3];
    float msk[RPT + 2][3];
    #pragma unroll
    for (int dy = 0; dy < RPT + 2; ++dy) {
        int yy = y0 + dy - 1;
        #pragma unroll
        for (int dx = 0; dx < 3; ++dx) {
            int xx = col + dx - 1;
            bool ok = (yy >= 0 && yy < H && xx >= 0 && xx < W);
            off[dy][dx] = ok ? yy * W + xx : 0;
            msk[dy][dx] = ok ? 1.0f : 0.0f;
        }
    }

    float z[RPT][OCL][4];
    #pragma unroll
    for (int r = 0; r < RPT; ++r)
        #pragma unroll
        for (int j = 0; j < OCL; ++j)
            #pragma unroll
            for (int g = 0; g < 4; ++g)
                z[r][j][g] = bias[g * hid + oc0 + j];

    const float* xsl = xin + ((size_t)(b * T + t0 + tc) * Cin) * HW;
    for (int ic = 0; ic < Cin; ++ic) {
        const float* src = xsl + (size_t)ic * HW;
        float v[RPT + 2][3];
        #pragma unroll
        for (int dy = 0; dy < RPT + 2; ++dy)
            #pragma unroll
            for (int dx = 0; dx < 3; ++dx)
                v[dy][dx] = src[off[dy][dx]] * msk[dy][dx];

        #pragma unroll
        for (int j = 0; j < OCL; ++j)
            #pragma unroll
            for (int g = 0; g < 4; ++g) {
                const float* wp = w + ((size_t)(g * hid + oc0 + j) * Ctot + ic) * 9;
                #pragma unroll
                for (int k = 0; k < 9; ++k) {
                    float wv = wp[k];
                    #pragma unroll
                    for (int r = 0; r < RPT; ++r)
                        z[r][j][g] = fmaf(v[r + k / 3][k % 3], wv, z[r][j][g]);
                }
            }
    }

    size_t base = ((size_t)(b * TcMax + tc) * 4 * hid) * HW;
    #pragma unroll
    for (int r = 0; r < RPT; ++r) {
        size_t rb = base + (size_t)(y0 + r) * W + col;
        #pragma unroll
        for (int j = 0; j < OCL; ++j)
            #pragma unroll
            for (int g = 0; g < 4; ++g)
                zx[rb + (size_t)(g * hid + oc0 + j) * HW] = z[r][j][g];
    }
}

// ---------------------------------------------------------------------------
// zx_lds (L1-L3): x-part conv with LDS-staged weights [ocl][ic][k][g]
// (float4 broadcast reads). TCB timesteps per block share the weight stage.
// ---------------------------------------------------------------------------
template<int TPB, int OCL, int CIN, int TCB>
__global__ __launch_bounds__(TPB) void zx_lds(
    const float* __restrict__ xin, const float* __restrict__ w,
    const float* __restrict__ bias, float* __restrict__ zx,
    int t0, int TcAct, int TcMax, int B, int T, int Ctot, int hid,
    int H, int W, int nOcg, int BPP, int nTcb)
{
    const int HW  = H * W;
    const int PIX = TPB / TCB;
    alignas(16) __shared__ float wlds[OCL * CIN * 36];

    int blk   = blockIdx.x;
    int chunk = blk % BPP;
    int ocg   = (blk / BPP) % nOcg;
    int tcb   = (blk / (BPP * nOcg)) % nTcb;
    int b     = blk / (BPP * nOcg * nTcb);
    int oc0   = ocg * OCL;

    for (int i = threadIdx.x; i < OCL * CIN * 36; i += TPB) {
        int g   = i & 3;
        int k   = (i >> 2) % 9;
        int ic  = (i / 36) % CIN;
        int ocl = i / (36 * CIN);
        wlds[i] = w[((size_t)(g * hid + oc0 + ocl) * Ctot + ic) * 9 + k];
    }
    __syncthreads();

    int tcl = threadIdx.x / PIX;
    int p   = threadIdx.x % PIX;
    int tc  = tcb * TCB + tcl;
    if (tc >= TcAct) return;

    int px  = chunk * PIX + p;
    int col = px % W;
    int y0  = px / W;

    int   off[3][3];
    float msk[3][3];
    #pragma unroll
    for (int dy = 0; dy < 3; ++dy) {
        int yy = y0 + dy - 1;
        #pragma unroll
        for (int dx = 0; dx < 3; ++dx) {
            int xx = col + dx - 1;
            bool ok = (yy >= 0 && yy < H && xx >= 0 && xx < W);
            off[dy][dx] = ok ? yy * W + xx : 0;
            msk[dy][dx] = ok ? 1.0f : 0.0f;
        }
    }

    float z[OCL][4];
    #pragma unroll
    for (int j = 0; j < OCL; ++j)
        #pragma unroll
        for (int g = 0; g < 4; ++g)
            z[j][g] = bias[g * hid + oc0 + j];

    const float* xsl = xin + ((size_t)(b * T + t0 + tc) * CIN) * HW;
    for (int ic = 0; ic < CIN; ++ic) {
        const float* src = xsl + (size_t)ic * HW;
        float v[3][3];
        #pragma unroll
        for (int dy = 0; dy < 3; ++dy)
            #pragma unroll
            for (int dx = 0; dx < 3; ++dx)
                v[dy][dx] = src[off[dy][dx]] * msk[dy][dx];

        #pragma unroll
        for (int j = 0; j < OCL; ++j) {
            #pragma unroll
            for (int k = 0; k < 9; ++k) {
                const float4 wv = *(const float4*)&wlds[(((j * CIN + ic) * 9) + k) * 4];
                float vv = v[k / 3][k % 3];
                z[j][0] = fmaf(vv, wv.x, z[j][0]);
                z[j][1] = fmaf(vv, wv.y, z[j][1]);
                z[j][2] = fmaf(vv, wv.z, z[j][2]);
                z[j][3] = fmaf(vv, wv.w, z[j][3]);
            }
        }
    }

    size_t base = ((size_t)(b * TcMax + tc) * 4 * hid) * HW + (size_t)y0 * W + col;
    #pragma unroll
    for (int j = 0; j < OCL; ++j)
        #pragma unroll
        for (int g = 0; g < 4; ++g)
            zx[base + (size_t)(g * hid + oc0 + j) * HW] = z[j][g];
}

// ---------------------------------------------------------------------------
// step_k: one ConvLSTM timestep. z = zx + conv3x3(h_{t-1}); gates; update.
// OCL=1, 1 px/thread for max TLP. SPLIT>1: ic range split across SPLIT
// thread-slices, LDS partial reduce, slice 0 does the state update.
// ---------------------------------------------------------------------------
template<int TPB, int OCL, int RPT, int HID, int SPLIT>
__global__ __launch_bounds__(TPB) void step_k(
    const float* __restrict__ zx,    // [B,TcMax,4,hid,H,W]
    const float* __restrict__ w,     // [4*hid, Ctot, 3, 3]
    float* __restrict__ hbuf,        // [B,T,hid,H,W]
    float* __restrict__ cbuf,        // [B,hid,H,W]
    int t, int tc, int TcMax, int B, int T, int Cin, int H, int W,
    int nOcg, int BPP)
{
    const int HW   = H * W;
    const int Ctot = Cin + HID;
    const int PIXT = TPB / SPLIT;
    const int ICB  = HID / SPLIT;
    alignas(16) __shared__ float wlds[OCL * HID * 36];
    __shared__ float zred[(SPLIT > 1) ? (TPB * RPT * OCL * 4) : 1];

    int blk   = blockIdx.x;
    int chunk = blk % BPP;
    int ocg   = (blk / BPP) % nOcg;
    int b     = blk / (BPP * nOcg);
    int oc0   = ocg * OCL;

    if (t > 0) {
        for (int i = threadIdx.x; i < OCL * HID * 36; i += TPB) {
            int g   = i & 3;
            int k   = (i >> 2) % 9;
            int ic  = (i / 36) % HID;
            int ocl = i / (36 * HID);
            wlds[i] = w[((size_t)(g * HID + oc0 + ocl) * Ctot + Cin + ic) * 9 + k];
        }
        __syncthreads();
    }

    int tid   = threadIdx.x;
    int slice = tid / PIXT;
    int p     = tid % PIXT;
    int col   = p % W;
    int rowg  = p / W;
    int rpc   = (PIXT / W) * RPT;
    int y0    = chunk * rpc + rowg * RPT;

    float z[RPT][OCL][4];
    if (slice == 0) {
        size_t zbase = ((size_t)(b * TcMax + tc) * 4 * HID) * HW;
        #pragma unroll
        for (int r = 0; r < RPT; ++r) {
            size_t rb = zbase + (size_t)(y0 + r) * W + col;
            #pragma unroll
            for (int j = 0; j < OCL; ++j)
                #pragma unroll
                for (int g = 0; g < 4; ++g)
                    z[r][j][g] = zx[rb + (size_t)(g * HID + oc0 + j) * HW];
        }
    } else {
        #pragma unroll
        for (int r = 0; r < RPT; ++r)
            #pragma unroll
            for (int j = 0; j < OCL; ++j)
                #pragma unroll
                for (int g = 0; g < 4; ++g)
                    z[r][j][g] = 0.0f;
    }

    if (t > 0) {
        int   off[RPT + 2][3];
        float msk[RPT + 2][3];
        #pragma unroll
        for (int dy = 0; dy < RPT + 2; ++dy) {
            int yy = y0 + dy - 1;
            #pragma unroll
            for (int dx = 0; dx < 3; ++dx) {
                int xx = col + dx - 1;
                bool ok = (yy >= 0 && yy < H && xx >= 0 && xx < W);
                off[dy][dx] = ok ? yy * W + xx : 0;
                msk[dy][dx] = ok ? 1.0f : 0.0f;
            }
        }

        const float* hsl = hbuf + ((size_t)(b * T + (t - 1)) * HID) * HW;
        int ic0 = slice * ICB;
        #pragma unroll 2
        for (int ii = 0; ii < ICB; ++ii) {
            int ic = ic0 + ii;
            const float* src = hsl + (size_t)ic * HW;
            float v[RPT + 2][3];
            #pragma unroll
            for (int dy = 0; dy < RPT + 2; ++dy)
                #pragma unroll
                for (int dx = 0; dx < 3; ++dx)
                    v[dy][dx] = src[off[dy][dx]] * msk[dy][dx];

            #pragma unroll
            for (int k = 0; k < 9; ++k) {
                #pragma unroll
                for (int j = 0; j < OCL; ++j) {
                    const float4 wv = *(const float4*)
                        &wlds[(((j * HID + ic) * 9) + k) * 4];
                    #pragma unroll
                    for (int r = 0; r < RPT; ++r) {
                        float vv = v[r + k / 3][k % 3];
                        z[r][j][0] = fmaf(vv, wv.x, z[r][j][0]);
                        z[r][j][1] = fmaf(vv, wv.y, z[r][j][1]);
                        z[r][j][2] = fmaf(vv, wv.z, z[r][j][2]);
                        z[r][j][3] = fmaf(vv, wv.w, z[r][j][3]);
                    }
                }
            }
        }

        if (SPLIT > 1) {
            #pragma unroll
            for (int r = 0; r < RPT; ++r)
                #pragma unroll
                for (int j = 0; j < OCL; ++j)
                    #pragma unroll
                    for (int g = 0; g < 4; ++g)
                        zred[((tid * RPT + r) * OCL + j) * 4 + g] = z[r][j][g];
            __syncthreads();
            if (slice == 0) {
                #pragma unroll
                for (int s = 1; s < SPLIT; ++s)
                    #pragma unroll
                    for (int r = 0; r < RPT; ++r)
                        #pragma unroll
                        for (int j = 0; j < OCL; ++j)
                            #pragma unroll
                            for (int g = 0; g < 4; ++g)
                                z[r][j][g] += zred[(((s * PIXT + p) * RPT + r) * OCL + j) * 4 + g];
            }
        }
    }

    if (slice == 0) {
        #pragma unroll
        for (int r = 0; r < RPT; ++r) {
            int y = y0 + r;
            #pragma unroll
            for (int j = 0; j < OCL; ++j) {
                int oc = oc0 + j;
                size_t ci = ((size_t)b * HID + oc) * HW + (size_t)y * W + col;
                float cprev = (t == 0) ? 0.0f : cbuf[ci];
                float ig = sigmoid_(z[r][j][0]);
                float fg = sigmoid_(z[r][j][1]);
                float og = sigmoid_(z[r][j][2]);
                float gg = tanh_(z[r][j][3]);
                float cn = fg * cprev + ig * gg;
                cbuf[ci] = cn;
                hbuf[((size_t)(b * T + t) * HID + oc) * HW + (size_t)y * W + col]
                    = og * tanh_(cn);
            }
        }
    }
}

// ---------------------------------------------------------------------------
// BatchNorm stats / BN+ReLU+Pool / FC head
// ---------------------------------------------------------------------------
__global__ void bn_stats(const float* __restrict__ hbuf, float* __restrict__ stats,
                         int BT, int C, int HW)
{
    int c = blockIdx.x;
    float s = 0.0f, s2 = 0.0f;
    for (int bt = blockIdx.y; bt < BT; bt += gridDim.y) {
        const float* p = hbuf + ((size_t)bt * C + c) * HW;
        for (int i = threadIdx.x; i < HW; i += blockDim.x) {
            float v = p[i];
            s += v;
            s2 += v * v;
        }
    }
    __shared__ float ssum[256];
    __shared__ float ssq[256];
    int tid = threadIdx.x;
    ssum[tid] = s; ssq[tid] = s2;
    __syncthreads();
    for (int off = 128; off > 0; off >>= 1) {
        if (tid < off) { ssum[tid] += ssum[tid + off]; ssq[tid] += ssq[tid + off]; }
        __syncthreads();
    }
    if (tid == 0) {
        atomicAdd(&stats[2 * c + 0], ssum[0]);
        atomicAdd(&stats[2 * c + 1], ssq[0]);
    }
}

__global__ void bn_relu_pool(const float* __restrict__ hbuf,
                             const float* __restrict__ stats,
                             const float* __restrict__ gamma,
                             const float* __restrict__ beta,
                             float* __restrict__ out,
                             int BT, int C, int H, int W, float invN)
{
    int Ho = H / 2, Wo = W / 2;
    int idx = blockIdx.x * blockDim.x + threadIdx.x;
    int total = BT * C * Ho * Wo;
    if (idx >= total) return;
    int xo = idx % Wo;
    int yo = (idx / Wo) % Ho;
    int c  = (idx / (Wo * Ho)) % C;
    int bt = idx / (C * Ho * Wo);

    float mean = stats[2 * c + 0] * invN;
    float var  = stats[2 * c + 1] * invN - mean * mean;
    float sc = gamma[c] * rsqrtf(var + 1e-5f);
    float sh = beta[c] - mean * sc;

    const float* p = hbuf + ((size_t)bt * C + c) * (H * W) + (2 * yo) * W + 2 * xo;
    float a0 = fmaxf(fmaf(p[0],     sc, sh), 0.0f);
    float a1 = fmaxf(fmaf(p[1],     sc, sh), 0.0f);
    float a2 = fmaxf(fmaf(p[W],     sc, sh), 0.0f);
    float a3 = fmaxf(fmaf(p[W + 1], sc, sh), 0.0f);
    out[idx] = fmaxf(fmaxf(a0, a1), fmaxf(a2, a3));
}

__global__ __launch_bounds__(128) void fc_head(const float* __restrict__ feat,
                                               const float* __restrict__ fc1w,
                                               const float* __restrict__ fc1b,
                                               const float* __restrict__ fc2w,
                                               const float* __restrict__ fc2b,
                                               float* __restrict__ out)
{
    __shared__ float sf[1024];
    __shared__ float y1[128];
    int bt = blockIdx.x;
    const float* f = feat + (size_t)bt * 1024;
    for (int i = threadIdx.x; i < 1024; i += 128) sf[i] = f[i];
    __syncthreads();
    int k = threadIdx.x;
    float acc = fc1b[k];
    const float* wk = fc1w + (size_t)k * 1024;
    for (int d = 0; d < 1024; ++d) acc = fmaf(sf[d], wk[d], acc);
    y1[k] = fmaxf(acc, 0.0f);
    __syncthreads();
    if (k < 2) {
        float a = fc2b[k];
        const float* w2 = fc2w + k * 128;
        for (int j = 0; j < 128; ++j) a = fmaf(y1[j], w2[j], a);
        out[(size_t)bt * 2 + k] = a;
    }
}

// ---------------------------------------------------------------------------
// Host
// ---------------------------------------------------------------------------
static void launch_zx(int l, const float* in, const float* w, const float* bias,
                      float* zbuf, int t0, int TcAct, int TcMax, int B, int T,
                      int Cin, int hid, int H, int W, hipStream_t s)
{
    int Ctot = Cin + hid;
    switch (l) {
        case 0: { // Cin=1: scalar weights fine. nOcg=4, BPP=4096/512=8
            zx_k<256,4,2><<<B*TcAct*4*8, 256, 0, s>>>(
                in,w,bias,zbuf,t0,TcAct,TcMax,B,T,Cin,Ctot,hid,H,W,4,8); } break;
        case 1: { // LDS weights, nOcg=8, BPP=1024/256=4, TCB=1
            zx_lds<256,4,16,1><<<B*TcAct*8*4, 256, 0, s>>>(
                in,w,bias,zbuf,t0,TcAct,TcMax,B,T,Ctot,hid,H,W,8,4,TcAct); } break;
        case 2: { // nOcg=16, BPP=1, TCB=1
            zx_lds<256,4,32,1><<<B*TcAct*16, 256, 0, s>>>(
                in,w,bias,zbuf,t0,TcAct,TcMax,B,T,Ctot,hid,H,W,16,1,TcAct); } break;
        case 3: { // nOcg=16, BPP=1, TCB=4 (4 timesteps share weight stage)
            int nTcb = (TcAct + 3) / 4;
            zx_lds<256,4,64,4><<<B*nTcb*16, 256, 0, s>>>(
                in,w,bias,zbuf,t0,TcAct,TcMax,B,T,Ctot,hid,H,W,16,1,nTcb); } break;
    }
}

static void launch_step(int l, const float* zbuf, const float* w,
                        float* hbuf, float* cbuf, int t, int tc, int TcMax,
                        int B, int T, int Cin, int hid, int H, int W, hipStream_t s)
{
    switch (l) {
        case 0: // 524288 outputs, 1/thread: nOcg=16, BPP=16 -> 2048 blocks
            step_k<256,1,1,16,1><<<2048,256,0,s>>>(zbuf,w,hbuf,cbuf,t,tc,TcMax,B,T,Cin,H,W,16,16); break;
        case 1: // 262144 outputs: nOcg=32, BPP=4 -> 1024 blocks
            step_k<256,1,1,32,1><<<1024,256,0,s>>>(zbuf,w,hbuf,cbuf,t,tc,TcMax,B,T,Cin,H,W,32,4); break;
        case 2: // 131072 outputs: nOcg=64, BPP=1 -> 512 blocks
            step_k<256,1,1,64,1><<< 512,256,0,s>>>(zbuf,w,hbuf,cbuf,t,tc,TcMax,B,T,Cin,H,W,64,1); break;
        case 3: // 32768 outputs x SPLIT=4 -> 131072 threads: 512 blocks
            step_k<256,1,1,64,4><<< 512,256,0,s>>>(zbuf,w,hbuf,cbuf,t,tc,TcMax,B,T,Cin,H,W,64,1); break;
    }
}

extern "C" void kernel_launch(void* const* d_in, const int* in_sizes, int n_in,
                              void* d_out, int out_size, void* d_ws, size_t ws_size,
                              hipStream_t stream)
{
    const int B = 8, T = 40;
    const float* x = (const float*)d_in[0];

    // workspace layout (floats); ~141 MB total (proven available)
    float* hbuf  = (float*)d_ws;                 // 20,971,520
    float* pbuf  = hbuf + (size_t)20971520;      //  5,242,880
    float* cbuf  = pbuf + (size_t)5242880;       //    524,288
    float* stats = cbuf + (size_t)524288;        //        128
    float* zbuf  = stats + 128;                  //  8,388,608

    struct LCfg { int Cin, hid, H, W, Tc; };
    const LCfg L[4] = { {1, 16, 64, 64, 4}, {16, 32, 32, 32, 8},
                        {32, 64, 16, 16, 16}, {64, 64, 8, 8, 40} };

    const float* in = x;
    for (int l = 0; l < 4; ++l) {
        const float* w     = (const float*)d_in[1 + 4 * l];
        const float* bias  = (const float*)d_in[2 + 4 * l];
        const float* gamma = (const float*)d_in[3 + 4 * l];
        const float* beta  = (const float*)d_in[4 + 4 * l];
        const int Cin = L[l].Cin, hid = L[l].hid, H = L[l].H, W = L[l].W;
        const int HW = H * W;
        const int TcMax = L[l].Tc;

        for (int t0 = 0; t0 < T; t0 += TcMax) {
            int TcAct = (T - t0 < TcMax) ? (T - t0) : TcMax;
            launch_zx(l, in, w, bias, zbuf, t0, TcAct, TcMax, B, T, Cin, hid, H, W, stream);
            for (int t = t0; t < t0 + TcAct; ++t)
                launch_step(l, zbuf, w, hbuf, cbuf, t, t - t0, TcMax,
                            B, T, Cin, hid, H, W, stream);
        }

        hipMemsetAsync(stats, 0, 2 * hid * sizeof(float), stream);
        bn_stats<<<dim3(hid, 80), 256, 0, stream>>>(hbuf, stats, B * T, hid, HW);

        int ptotal = B * T * hid * (H / 2) * (W / 2);
        float invN = 1.0f / ((float)(B * T) * (float)HW);
        bn_relu_pool<<<(ptotal + 255) / 256, 256, 0, stream>>>(
            hbuf, stats, gamma, beta, pbuf, B * T, hid, H, W, invN);
        in = pbuf;
    }

    const float* fc1w = (const float*)d_in[17];
    const float* fc1b = (const float*)d_in[18];
    const float* fc2w = (const float*)d_in[19];
    const float* fc2b = (const float*)d_in[20];
    fc_head<<<B * T, 128, 0, stream>>>(pbuf, fc1w, fc1b, fc2w, fc2b, (float*)d_out);
}

// Round 13
// 5474.977 us; speedup vs baseline: 1.4807x; 1.4807x over previous
//
#include <hip/hip_runtime.h>
#include <math.h>

#define DEV __device__ __forceinline__

DEV float sigmoid_(float x) { return 1.0f / (1.0f + __expf(-x)); }
DEV float tanh_(float x) {
    float e = __expf(2.0f * x);
    return 1.0f - 2.0f / (e + 1.0f);
}

// ---------------------------------------------------------------------------
// zx_k (scalar-weight; only for L0 where Cin==1): z_x = bias + conv3x3(x_t).
// zx layout: [B,TcMax,4,hid,H,W]   [measured r10/r12: fine for Cin=1]
// ---------------------------------------------------------------------------
template<int TPB, int OCL, int RPT>
__global__ __launch_bounds__(TPB) void zx_k(
    const float* __restrict__ xin, const float* __restrict__ w,
    const float* __restrict__ bias, float* __restrict__ zx,
    int t0, int TcAct, int TcMax, int B, int T, int Cin, int Ctot,
    int hid, int H, int W, int nOcg, int BPP)
{
    const int HW = H * W;
    int blk   = blockIdx.x;
    int chunk = blk % BPP;
    int ocg   = (blk / BPP) % nOcg;
    int tc    = (blk / (BPP * nOcg)) % TcAct;
    int b     = blk / (BPP * nOcg * TcAct);
    int oc0   = ocg * OCL;

    int p    = threadIdx.x;
    int col  = p % W;
    int rowg = p / W;
    int rpc  = (TPB / W) * RPT;
    int y0   = chunk * rpc + rowg * RPT;

    int   off[RPT + 2][3];
    float msk[RPT + 2][3];
    #pragma unroll
    for (int dy = 0; dy < RPT + 2; ++dy) {
        int yy = y0 + dy - 1;
        #pragma unroll
        for (int dx = 0; dx < 3; ++dx) {
            int xx = col + dx - 1;
            bool ok = (yy >= 0 && yy < H && xx >= 0 && xx < W);
            off[dy][dx] = ok ? yy * W + xx : 0;
            msk[dy][dx] = ok ? 1.0f : 0.0f;
        }
    }

    float z[RPT][OCL][4];
    #pragma unroll
    for (int r = 0; r < RPT; ++r)
        #pragma unroll
        for (int j = 0; j < OCL; ++j)
            #pragma unroll
            for (int g = 0; g < 4; ++g)
                z[r][j][g] = bias[g * hid + oc0 + j];

    const float* xsl = xin + ((size_t)(b * T + t0 + tc) * Cin) * HW;
    for (int ic = 0; ic < Cin; ++ic) {
        const float* src = xsl + (size_t)ic * HW;
        float v[RPT + 2][3];
        #pragma unroll
        for (int dy = 0; dy < RPT + 2; ++dy)
            #pragma unroll
            for (int dx = 0; dx < 3; ++dx)
                v[dy][dx] = src[off[dy][dx]] * msk[dy][dx];

        #pragma unroll
        for (int j = 0; j < OCL; ++j)
            #pragma unroll
            for (int g = 0; g < 4; ++g) {
                const float* wp = w + ((size_t)(g * hid + oc0 + j) * Ctot + ic) * 9;
                #pragma unroll
                for (int k = 0; k < 9; ++k) {
                    float wv = wp[k];
                    #pragma unroll
                    for (int r = 0; r < RPT; ++r)
                        z[r][j][g] = fmaf(v[r + k / 3][k % 3], wv, z[r][j][g]);
                }
            }
    }

    size_t base = ((size_t)(b * TcMax + tc) * 4 * hid) * HW;
    #pragma unroll
    for (int r = 0; r < RPT; ++r) {
        size_t rb = base + (size_t)(y0 + r) * W + col;
        #pragma unroll
        for (int j = 0; j < OCL; ++j)
            #pragma unroll
            for (int g = 0; g < 4; ++g)
                zx[rb + (size_t)(g * hid + oc0 + j) * HW] = z[r][j][g];
    }
}

// ---------------------------------------------------------------------------
// zx_lds (L1-L3): x-part conv with LDS-staged weights [ocl][ic][k][g]
// (float4 broadcast reads). TCB timesteps per block share the weight stage.
// [measured r12: L3 145us @ VALUBusy 63% vs 210us scalar-weight]
// ---------------------------------------------------------------------------
template<int TPB, int OCL, int CIN, int TCB>
__global__ __launch_bounds__(TPB) void zx_lds(
    const float* __restrict__ xin, const float* __restrict__ w,
    const float* __restrict__ bias, float* __restrict__ zx,
    int t0, int TcAct, int TcMax, int B, int T, int Ctot, int hid,
    int H, int W, int nOcg, int BPP, int nTcb)
{
    const int HW  = H * W;
    const int PIX = TPB / TCB;
    alignas(16) __shared__ float wlds[OCL * CIN * 36];

    int blk   = blockIdx.x;
    int chunk = blk % BPP;
    int ocg   = (blk / BPP) % nOcg;
    int tcb   = (blk / (BPP * nOcg)) % nTcb;
    int b     = blk / (BPP * nOcg * nTcb);
    int oc0   = ocg * OCL;

    for (int i = threadIdx.x; i < OCL * CIN * 36; i += TPB) {
        int g   = i & 3;
        int k   = (i >> 2) % 9;
        int ic  = (i / 36) % CIN;
        int ocl = i / (36 * CIN);
        wlds[i] = w[((size_t)(g * hid + oc0 + ocl) * Ctot + ic) * 9 + k];
    }
    __syncthreads();

    int tcl = threadIdx.x / PIX;
    int p   = threadIdx.x % PIX;
    int tc  = tcb * TCB + tcl;
    if (tc >= TcAct) return;

    int px  = chunk * PIX + p;
    int col = px % W;
    int y0  = px / W;

    int   off[3][3];
    float msk[3][3];
    #pragma unroll
    for (int dy = 0; dy < 3; ++dy) {
        int yy = y0 + dy - 1;
        #pragma unroll
        for (int dx = 0; dx < 3; ++dx) {
            int xx = col + dx - 1;
            bool ok = (yy >= 0 && yy < H && xx >= 0 && xx < W);
            off[dy][dx] = ok ? yy * W + xx : 0;
            msk[dy][dx] = ok ? 1.0f : 0.0f;
        }
    }

    float z[OCL][4];
    #pragma unroll
    for (int j = 0; j < OCL; ++j)
        #pragma unroll
        for (int g = 0; g < 4; ++g)
            z[j][g] = bias[g * hid + oc0 + j];

    const float* xsl = xin + ((size_t)(b * T + t0 + tc) * CIN) * HW;
    for (int ic = 0; ic < CIN; ++ic) {
        const float* src = xsl + (size_t)ic * HW;
        float v[3][3];
        #pragma unroll
        for (int dy = 0; dy < 3; ++dy)
            #pragma unroll
            for (int dx = 0; dx < 3; ++dx)
                v[dy][dx] = src[off[dy][dx]] * msk[dy][dx];

        #pragma unroll
        for (int j = 0; j < OCL; ++j) {
            #pragma unroll
            for (int k = 0; k < 9; ++k) {
                const float4 wv = *(const float4*)&wlds[(((j * CIN + ic) * 9) + k) * 4];
                float vv = v[k / 3][k % 3];
                z[j][0] = fmaf(vv, wv.x, z[j][0]);
                z[j][1] = fmaf(vv, wv.y, z[j][1]);
                z[j][2] = fmaf(vv, wv.z, z[j][2]);
                z[j][3] = fmaf(vv, wv.w, z[j][3]);
            }
        }
    }

    size_t base = ((size_t)(b * TcMax + tc) * 4 * hid) * HW + (size_t)y0 * W + col;
    #pragma unroll
    for (int j = 0; j < OCL; ++j)
        #pragma unroll
        for (int g = 0; g < 4; ++g)
            zx[base + (size_t)(g * hid + oc0 + j) * HW] = z[j][g];
}

// ---------------------------------------------------------------------------
// step_h: one ConvLSTM timestep — EXACT round-3-measured structure (6988us
// total, ~27us/step): OCB oc-channels per block (oc uniform per wave), LDS
// weights [ocb][ic][36] with wave-uniform broadcast reads, runtime hid loop,
// ternary bounds checks. Blocks: 1024/512/512/128.
// ---------------------------------------------------------------------------
template<int TPB, int OCB, int RPT>
__global__ __launch_bounds__(TPB) void step_h(
    const float* __restrict__ zx,    // [B,TcMax,4,hid,H,W]
    const float* __restrict__ w,     // [4*hid, Ctot, 3, 3]
    float* __restrict__ hbuf,        // [B,T,hid,H,W]
    float* __restrict__ cbuf,        // [B,hid,H,W]
    int t, int tc, int TcMax, int B, int T, int Cin, int hid, int H, int W,
    int nOcg, int BPP)
{
    extern __shared__ float wlds[];  // [OCB][hid][36]
    const int HW = H * W;
    const int Ctot = Cin + hid;

    int blk   = blockIdx.x;
    int chunk = blk % BPP;
    int ocg   = (blk / BPP) % nOcg;
    int b     = blk / (BPP * nOcg);
    int oc0   = ocg * OCB;

    if (t > 0) {
        int tot = OCB * hid * 36;
        for (int i = threadIdx.x; i < tot; i += TPB) {
            int ocb = i / (hid * 36);
            int rem = i % (hid * 36);
            int ic  = rem / 36;
            int gk  = rem % 36;
            int g = gk / 9, k = gk % 9;
            wlds[i] = w[((size_t)(g * hid + oc0 + ocb) * Ctot + Cin + ic) * 9 + k];
        }
        __syncthreads();
    }

    const int TPO = TPB / OCB;          // threads per output channel
    int ocb  = threadIdx.x / TPO;
    int p    = threadIdx.x % TPO;
    int oc   = oc0 + ocb;
    int col  = p % W;
    int rowg = p / W;
    const int chunkRows = (TPO / W) * RPT;
    int y0 = chunk * chunkRows + rowg * RPT;

    float z[RPT][4];
    size_t zb0 = ((size_t)(b * TcMax + tc) * 4 * hid) * HW;
    #pragma unroll
    for (int r = 0; r < RPT; ++r) {
        size_t zb = zb0 + (size_t)(y0 + r) * W + col;
        #pragma unroll
        for (int g = 0; g < 4; ++g)
            z[r][g] = zx[zb + (size_t)(g * hid + oc) * HW];
    }

    if (t > 0) {
        const float* hsl = hbuf + ((size_t)(b * T + (t - 1)) * hid) * HW;
        for (int ic = 0; ic < hid; ++ic) {
            const float* src = hsl + (size_t)ic * HW;
            float v[RPT + 2][3];
            #pragma unroll
            for (int dy = 0; dy < RPT + 2; ++dy) {
                int yy = y0 + dy - 1;
                #pragma unroll
                for (int dx = 0; dx < 3; ++dx) {
                    int xx = col + dx - 1;
                    v[dy][dx] = (yy >= 0 && yy < H && xx >= 0 && xx < W)
                                ? src[yy * W + xx] : 0.0f;
                }
            }
            float wv[36];
            const float* wp = &wlds[(ocb * hid + ic) * 36];
            #pragma unroll
            for (int j = 0; j < 36; ++j) wv[j] = wp[j];
            #pragma unroll
            for (int r = 0; r < RPT; ++r)
                #pragma unroll
                for (int g = 0; g < 4; ++g)
                    #pragma unroll
                    for (int k = 0; k < 9; ++k)
                        z[r][g] = fmaf(v[r + k / 3][k % 3], wv[g * 9 + k], z[r][g]);
        }
    }

    #pragma unroll
    for (int r = 0; r < RPT; ++r) {
        int y = y0 + r;
        size_t ci = ((size_t)b * hid + oc) * HW + (size_t)y * W + col;
        float cprev = (t == 0) ? 0.0f : cbuf[ci];
        float ig = sigmoid_(z[r][0]);
        float fg = sigmoid_(z[r][1]);
        float og = sigmoid_(z[r][2]);
        float gg = tanh_(z[r][3]);
        float cn = fg * cprev + ig * gg;
        cbuf[ci] = cn;
        hbuf[((size_t)(b * T + t) * hid + oc) * HW + (size_t)y * W + col]
            = og * tanh_(cn);
    }
}

// ---------------------------------------------------------------------------
// BatchNorm stats / BN+ReLU+Pool / FC head (unchanged, measured fine)
// ---------------------------------------------------------------------------
__global__ void bn_stats(const float* __restrict__ hbuf, float* __restrict__ stats,
                         int BT, int C, int HW)
{
    int c = blockIdx.x;
    float s = 0.0f, s2 = 0.0f;
    for (int bt = blockIdx.y; bt < BT; bt += gridDim.y) {
        const float* p = hbuf + ((size_t)bt * C + c) * HW;
        for (int i = threadIdx.x; i < HW; i += blockDim.x) {
            float v = p[i];
            s += v;
            s2 += v * v;
        }
    }
    __shared__ float ssum[256];
    __shared__ float ssq[256];
    int tid = threadIdx.x;
    ssum[tid] = s; ssq[tid] = s2;
    __syncthreads();
    for (int off = 128; off > 0; off >>= 1) {
        if (tid < off) { ssum[tid] += ssum[tid + off]; ssq[tid] += ssq[tid + off]; }
        __syncthreads();
    }
    if (tid == 0) {
        atomicAdd(&stats[2 * c + 0], ssum[0]);
        atomicAdd(&stats[2 * c + 1], ssq[0]);
    }
}

__global__ void bn_relu_pool(const float* __restrict__ hbuf,
                             const float* __restrict__ stats,
                             const float* __restrict__ gamma,
                             const float* __restrict__ beta,
                             float* __restrict__ out,
                             int BT, int C, int H, int W, float invN)
{
    int Ho = H / 2, Wo = W / 2;
    int idx = blockIdx.x * blockDim.x + threadIdx.x;
    int total = BT * C * Ho * Wo;
    if (idx >= total) return;
    int xo = idx % Wo;
    int yo = (idx / Wo) % Ho;
    int c  = (idx / (Wo * Ho)) % C;
    int bt = idx / (C * Ho * Wo);

    float mean = stats[2 * c + 0] * invN;
    float var  = stats[2 * c + 1] * invN - mean * mean;
    float sc = gamma[c] * rsqrtf(var + 1e-5f);
    float sh = beta[c] - mean * sc;

    const float* p = hbuf + ((size_t)bt * C + c) * (H * W) + (2 * yo) * W + 2 * xo;
    float a0 = fmaxf(fmaf(p[0],     sc, sh), 0.0f);
    float a1 = fmaxf(fmaf(p[1],     sc, sh), 0.0f);
    float a2 = fmaxf(fmaf(p[W],     sc, sh), 0.0f);
    float a3 = fmaxf(fmaf(p[W + 1], sc, sh), 0.0f);
    out[idx] = fmaxf(fmaxf(a0, a1), fmaxf(a2, a3));
}

__global__ __launch_bounds__(128) void fc_head(const float* __restrict__ feat,
                                               const float* __restrict__ fc1w,
                                               const float* __restrict__ fc1b,
                                               const float* __restrict__ fc2w,
                                               const float* __restrict__ fc2b,
                                               float* __restrict__ out)
{
    __shared__ float sf[1024];
    __shared__ float y1[128];
    int bt = blockIdx.x;
    const float* f = feat + (size_t)bt * 1024;
    for (int i = threadIdx.x; i < 1024; i += 128) sf[i] = f[i];
    __syncthreads();
    int k = threadIdx.x;
    float acc = fc1b[k];
    const float* wk = fc1w + (size_t)k * 1024;
    for (int d = 0; d < 1024; ++d) acc = fmaf(sf[d], wk[d], acc);
    y1[k] = fmaxf(acc, 0.0f);
    __syncthreads();
    if (k < 2) {
        float a = fc2b[k];
        const float* w2 = fc2w + k * 128;
        for (int j = 0; j < 128; ++j) a = fmaf(y1[j], w2[j], a);
        out[(size_t)bt * 2 + k] = a;
    }
}

// ---------------------------------------------------------------------------
// Host
// ---------------------------------------------------------------------------
static void launch_zx(int l, const float* in, const float* w, const float* bias,
                      float* zbuf, int t0, int TcAct, int TcMax, int B, int T,
                      int Cin, int hid, int H, int W, hipStream_t s)
{
    int Ctot = Cin + hid;
    switch (l) {
        case 0: { // Cin=1: scalar weights fine. nOcg=4, BPP=8
            zx_k<256,4,2><<<B*TcAct*4*8, 256, 0, s>>>(
                in,w,bias,zbuf,t0,TcAct,TcMax,B,T,Cin,Ctot,hid,H,W,4,8); } break;
        case 1: { // LDS weights, nOcg=8, BPP=4
            zx_lds<256,4,16,1><<<B*TcAct*8*4, 256, 0, s>>>(
                in,w,bias,zbuf,t0,TcAct,TcMax,B,T,Ctot,hid,H,W,8,4,TcAct); } break;
        case 2: { // nOcg=16, BPP=1
            zx_lds<256,4,32,1><<<B*TcAct*16, 256, 0, s>>>(
                in,w,bias,zbuf,t0,TcAct,TcMax,B,T,Ctot,hid,H,W,16,1,TcAct); } break;
        case 3: { // nOcg=16, BPP=1, TCB=4
            int nTcb = (TcAct + 3) / 4;
            zx_lds<256,4,64,4><<<B*nTcb*16, 256, 0, s>>>(
                in,w,bias,zbuf,t0,TcAct,TcMax,B,T,Ctot,hid,H,W,16,1,nTcb); } break;
    }
}

static void launch_step(int l, const float* zbuf, const float* w,
                        float* hbuf, float* cbuf, int t, int tc, int TcMax,
                        int B, int T, int Cin, int hid, int H, int W, hipStream_t s)
{
    // exact round-3 geometry (measured 6988us / ~27us per step)
    const int HW = H * W;
    const int OCB = (l == 3) ? 4 : 1;
    const int RPT = (l < 2) ? 2 : 1;
    const int TPO = 256 / OCB;
    const int CH  = TPO * RPT;
    const int BPP = HW / CH;
    const int nOcg = hid / OCB;
    const int blocks = B * nOcg * BPP;
    const size_t lds = (size_t)OCB * hid * 36 * sizeof(float);

    switch (l) {
        case 0: step_h<256,1,2><<<blocks,256,lds,s>>>(zbuf,w,hbuf,cbuf,t,tc,TcMax,B,T,Cin,hid,H,W,nOcg,BPP); break;
        case 1: step_h<256,1,2><<<blocks,256,lds,s>>>(zbuf,w,hbuf,cbuf,t,tc,TcMax,B,T,Cin,hid,H,W,nOcg,BPP); break;
        case 2: step_h<256,1,1><<<blocks,256,lds,s>>>(zbuf,w,hbuf,cbuf,t,tc,TcMax,B,T,Cin,hid,H,W,nOcg,BPP); break;
        case 3: step_h<256,4,1><<<blocks,256,lds,s>>>(zbuf,w,hbuf,cbuf,t,tc,TcMax,B,T,Cin,hid,H,W,nOcg,BPP); break;
    }
}

extern "C" void kernel_launch(void* const* d_in, const int* in_sizes, int n_in,
                              void* d_out, int out_size, void* d_ws, size_t ws_size,
                              hipStream_t stream)
{
    const int B = 8, T = 40;
    const float* x = (const float*)d_in[0];

    // workspace layout (floats); ~141 MB total (proven available)
    float* hbuf  = (float*)d_ws;                 // 20,971,520
    float* pbuf  = hbuf + (size_t)20971520;      //  5,242,880
    float* cbuf  = pbuf + (size_t)5242880;       //    524,288
    float* stats = cbuf + (size_t)524288;        //        128
    float* zbuf  = stats + 128;                  //  8,388,608

    struct LCfg { int Cin, hid, H, W, Tc; };
    const LCfg L[4] = { {1, 16, 64, 64, 4}, {16, 32, 32, 32, 8},
                        {32, 64, 16, 16, 16}, {64, 64, 8, 8, 40} };

    const float* in = x;
    for (int l = 0; l < 4; ++l) {
        const float* w     = (const float*)d_in[1 + 4 * l];
        const float* bias  = (const float*)d_in[2 + 4 * l];
        const float* gamma = (const float*)d_in[3 + 4 * l];
        const float* beta  = (const float*)d_in[4 + 4 * l];
        const int Cin = L[l].Cin, hid = L[l].hid, H = L[l].H, W = L[l].W;
        const int HW = H * W;
        const int TcMax = L[l].Tc;

        for (int t0 = 0; t0 < T; t0 += TcMax) {
            int TcAct = (T - t0 < TcMax) ? (T - t0) : TcMax;
            launch_zx(l, in, w, bias, zbuf, t0, TcAct, TcMax, B, T, Cin, hid, H, W, stream);
            for (int t = t0; t < t0 + TcAct; ++t)
                launch_step(l, zbuf, w, hbuf, cbuf, t, t - t0, TcMax,
                            B, T, Cin, hid, H, W, stream);
        }

        hipMemsetAsync(stats, 0, 2 * hid * sizeof(float), stream);
        bn_stats<<<dim3(hid, 80), 256, 0, stream>>>(hbuf, stats, B * T, hid, HW);

        int ptotal = B * T * hid * (H / 2) * (W / 2);
        float invN = 1.0f / ((float)(B * T) * (float)HW);
        bn_relu_pool<<<(ptotal + 255) / 256, 256, 0, stream>>>(
            hbuf, stats, gamma, beta, pbuf, B * T, hid, H, W, invN);
        in = pbuf;
    }

    const float* fc1w = (const float*)d_in[17];
    const float* fc1b = (const float*)d_in[18];
    const float* fc2w = (const float*)d_in[19];
    const float* fc2b = (const float*)d_in[20];
    fc_head<<<B * T, 128, 0, stream>>>(pbuf, fc1w, fc1b, fc2w, fc2b, (float*)d_out);
}

// Round 14
// 5255.119 us; speedup vs baseline: 1.5426x; 1.0418x over previous
//
#include <hip/hip_runtime.h>
#include <math.h>

#define DEV __device__ __forceinline__

DEV float sigmoid_(float x) { return 1.0f / (1.0f + __expf(-x)); }
DEV float tanh_(float x) {
    float e = __expf(2.0f * x);
    return 1.0f - 2.0f / (e + 1.0f);
}

// ---------------------------------------------------------------------------
// zx_k (scalar-weight; only for L0 where Cin==1): z_x = bias + conv3x3(x_t).
// zx layout: [B,TcMax,4,hid,H,W]   [measured r10/r12: fine for Cin=1]
// ---------------------------------------------------------------------------
template<int TPB, int OCL, int RPT>
__global__ __launch_bounds__(TPB) void zx_k(
    const float* __restrict__ xin, const float* __restrict__ w,
    const float* __restrict__ bias, float* __restrict__ zx,
    int t0, int TcAct, int TcMax, int B, int T, int Cin, int Ctot,
    int hid, int H, int W, int nOcg, int BPP)
{
    const int HW = H * W;
    int blk   = blockIdx.x;
    int chunk = blk % BPP;
    int ocg   = (blk / BPP) % nOcg;
    int tc    = (blk / (BPP * nOcg)) % TcAct;
    int b     = blk / (BPP * nOcg * TcAct);
    int oc0   = ocg * OCL;

    int p    = threadIdx.x;
    int col  = p % W;
    int rowg = p / W;
    int rpc  = (TPB / W) * RPT;
    int y0   = chunk * rpc + rowg * RPT;

    int   off[RPT + 2][3];
    float msk[RPT + 2][3];
    #pragma unroll
    for (int dy = 0; dy < RPT + 2; ++dy) {
        int yy = y0 + dy - 1;
        #pragma unroll
        for (int dx = 0; dx < 3; ++dx) {
            int xx = col + dx - 1;
            bool ok = (yy >= 0 && yy < H && xx >= 0 && xx < W);
            off[dy][dx] = ok ? yy * W + xx : 0;
            msk[dy][dx] = ok ? 1.0f : 0.0f;
        }
    }

    float z[RPT][OCL][4];
    #pragma unroll
    for (int r = 0; r < RPT; ++r)
        #pragma unroll
        for (int j = 0; j < OCL; ++j)
            #pragma unroll
            for (int g = 0; g < 4; ++g)
                z[r][j][g] = bias[g * hid + oc0 + j];

    const float* xsl = xin + ((size_t)(b * T + t0 + tc) * Cin) * HW;
    for (int ic = 0; ic < Cin; ++ic) {
        const float* src = xsl + (size_t)ic * HW;
        float v[RPT + 2][3];
        #pragma unroll
        for (int dy = 0; dy < RPT + 2; ++dy)
            #pragma unroll
            for (int dx = 0; dx < 3; ++dx)
                v[dy][dx] = src[off[dy][dx]] * msk[dy][dx];

        #pragma unroll
        for (int j = 0; j < OCL; ++j)
            #pragma unroll
            for (int g = 0; g < 4; ++g) {
                const float* wp = w + ((size_t)(g * hid + oc0 + j) * Ctot + ic) * 9;
                #pragma unroll
                for (int k = 0; k < 9; ++k) {
                    float wv = wp[k];
                    #pragma unroll
                    for (int r = 0; r < RPT; ++r)
                        z[r][j][g] = fmaf(v[r + k / 3][k % 3], wv, z[r][j][g]);
                }
            }
    }

    size_t base = ((size_t)(b * TcMax + tc) * 4 * hid) * HW;
    #pragma unroll
    for (int r = 0; r < RPT; ++r) {
        size_t rb = base + (size_t)(y0 + r) * W + col;
        #pragma unroll
        for (int j = 0; j < OCL; ++j)
            #pragma unroll
            for (int g = 0; g < 4; ++g)
                zx[rb + (size_t)(g * hid + oc0 + j) * HW] = z[r][j][g];
    }
}

// ---------------------------------------------------------------------------
// zx_lds (L1-L3): x-part conv with LDS-staged weights [ocl][ic][k][g]
// (float4 broadcast reads). TCB timesteps per block share the weight stage.
// [measured r12/r13: L3 ~145us @ VALUBusy 63%]
// ---------------------------------------------------------------------------
template<int TPB, int OCL, int CIN, int TCB>
__global__ __launch_bounds__(TPB) void zx_lds(
    const float* __restrict__ xin, const float* __restrict__ w,
    const float* __restrict__ bias, float* __restrict__ zx,
    int t0, int TcAct, int TcMax, int B, int T, int Ctot, int hid,
    int H, int W, int nOcg, int BPP, int nTcb)
{
    const int HW  = H * W;
    const int PIX = TPB / TCB;
    alignas(16) __shared__ float wlds[OCL * CIN * 36];

    int blk   = blockIdx.x;
    int chunk = blk % BPP;
    int ocg   = (blk / BPP) % nOcg;
    int tcb   = (blk / (BPP * nOcg)) % nTcb;
    int b     = blk / (BPP * nOcg * nTcb);
    int oc0   = ocg * OCL;

    for (int i = threadIdx.x; i < OCL * CIN * 36; i += TPB) {
        int g   = i & 3;
        int k   = (i >> 2) % 9;
        int ic  = (i / 36) % CIN;
        int ocl = i / (36 * CIN);
        wlds[i] = w[((size_t)(g * hid + oc0 + ocl) * Ctot + ic) * 9 + k];
    }
    __syncthreads();

    int tcl = threadIdx.x / PIX;
    int p   = threadIdx.x % PIX;
    int tc  = tcb * TCB + tcl;
    if (tc >= TcAct) return;

    int px  = chunk * PIX + p;
    int col = px % W;
    int y0  = px / W;

    int   off[3][3];
    float msk[3][3];
    #pragma unroll
    for (int dy = 0; dy < 3; ++dy) {
        int yy = y0 + dy - 1;
        #pragma unroll
        for (int dx = 0; dx < 3; ++dx) {
            int xx = col + dx - 1;
            bool ok = (yy >= 0 && yy < H && xx >= 0 && xx < W);
            off[dy][dx] = ok ? yy * W + xx : 0;
            msk[dy][dx] = ok ? 1.0f : 0.0f;
        }
    }

    float z[OCL][4];
    #pragma unroll
    for (int j = 0; j < OCL; ++j)
        #pragma unroll
        for (int g = 0; g < 4; ++g)
            z[j][g] = bias[g * hid + oc0 + j];

    const float* xsl = xin + ((size_t)(b * T + t0 + tc) * CIN) * HW;
    for (int ic = 0; ic < CIN; ++ic) {
        const float* src = xsl + (size_t)ic * HW;
        float v[3][3];
        #pragma unroll
        for (int dy = 0; dy < 3; ++dy)
            #pragma unroll
            for (int dx = 0; dx < 3; ++dx)
                v[dy][dx] = src[off[dy][dx]] * msk[dy][dx];

        #pragma unroll
        for (int j = 0; j < OCL; ++j) {
            #pragma unroll
            for (int k = 0; k < 9; ++k) {
                const float4 wv = *(const float4*)&wlds[(((j * CIN + ic) * 9) + k) * 4];
                float vv = v[k / 3][k % 3];
                z[j][0] = fmaf(vv, wv.x, z[j][0]);
                z[j][1] = fmaf(vv, wv.y, z[j][1]);
                z[j][2] = fmaf(vv, wv.z, z[j][2]);
                z[j][3] = fmaf(vv, wv.w, z[j][3]);
            }
        }
    }

    size_t base = ((size_t)(b * TcMax + tc) * 4 * hid) * HW + (size_t)y0 * W + col;
    #pragma unroll
    for (int j = 0; j < OCL; ++j)
        #pragma unroll
        for (int g = 0; g < 4; ++g)
            zx[base + (size_t)(g * hid + oc0 + j) * HW] = z[j][g];
}

// ---------------------------------------------------------------------------
// step_t: one ConvLSTM timestep with LDS h-tile.
// h[t-1] tile staged ONCE per block into zero-padded LDS [HID][ROWS+2][W+2]
// (kills 9x neighborhood re-reads + all inner-loop bounds checks); OCB=4
// output channels share the tile (kills 4x of the oc re-read amplification).
// TPO = ROWS*W = 64 = one wave per oc -> ocb wave-uniform -> weight reads are
// conflict-free float4 broadcasts from [ocb][ic][k][g].
// ---------------------------------------------------------------------------
template<int TPB, int OCB, int ROWS, int HID, int H, int W>
__global__ __launch_bounds__(TPB) void step_t(
    const float* __restrict__ zx,    // [B,TcMax,4,HID,H,W]
    const float* __restrict__ w,     // [4*HID, Ctot, 3, 3]
    float* __restrict__ hbuf,        // [B,T,HID,H,W]
    float* __restrict__ cbuf,        // [B,HID,H,W]
    int t, int tc, int TcMax, int B, int T, int Cin, int nOcg, int BPP)
{
    const int HW = H * W;
    const int Ctot = Cin + HID;
    const int TH = ROWS + 2, TW = W + 2;
    __shared__ float tile[HID][TH][TW];
    alignas(16) __shared__ float wlds[OCB][HID][9][4];

    int blk   = blockIdx.x;
    int chunk = blk % BPP;
    int ocg   = (blk / BPP) % nOcg;
    int b     = blk / (BPP * nOcg);
    int oc0   = ocg * OCB;
    int y0    = chunk * ROWS;

    if (t > 0) {
        // weights -> LDS, layout [ocb][ic][k][g]
        for (int i = threadIdx.x; i < OCB * HID * 36; i += TPB) {
            int g   = i & 3;
            int k   = (i >> 2) % 9;
            int ic  = (i / 36) % HID;
            int ocb = i / (36 * HID);
            ((float*)wlds)[i] =
                w[((size_t)(g * HID + oc0 + ocb) * Ctot + Cin + ic) * 9 + k];
        }
        // h tile -> LDS, zero-padded halo
        const float* hsl = hbuf + ((size_t)(b * T + (t - 1)) * HID) * HW;
        for (int i = threadIdx.x; i < HID * TH * TW; i += TPB) {
            int rx = i % TW;
            int ry = (i / TW) % TH;
            int ic = i / (TW * TH);
            int gy = y0 + ry - 1;
            int gx = rx - 1;
            float val = 0.0f;
            if (gy >= 0 && gy < H && gx >= 0 && gx < W)
                val = hsl[(size_t)ic * HW + gy * W + gx];
            ((float*)tile)[i] = val;
        }
        __syncthreads();
    }

    const int TPO = TPB / OCB;       // = ROWS*W = 64
    int ocb = threadIdx.x / TPO;     // wave-uniform
    int p   = threadIdx.x % TPO;
    int r   = p / W;
    int x   = p % W;
    int oc  = oc0 + ocb;
    int y   = y0 + r;

    float z[4];
    size_t zb = ((size_t)(b * TcMax + tc) * 4 * HID) * HW + (size_t)y * W + x;
    #pragma unroll
    for (int g = 0; g < 4; ++g)
        z[g] = zx[zb + (size_t)(g * HID + oc) * HW];

    if (t > 0) {
        for (int ic = 0; ic < HID; ++ic) {
            float v[3][3];
            #pragma unroll
            for (int dy = 0; dy < 3; ++dy)
                #pragma unroll
                for (int dx = 0; dx < 3; ++dx)
                    v[dy][dx] = tile[ic][r + dy][x + dx];
            #pragma unroll
            for (int k = 0; k < 9; ++k) {
                const float4 wv = *(const float4*)&wlds[ocb][ic][k][0];
                float vv = v[k / 3][k % 3];
                z[0] = fmaf(vv, wv.x, z[0]);
                z[1] = fmaf(vv, wv.y, z[1]);
                z[2] = fmaf(vv, wv.z, z[2]);
                z[3] = fmaf(vv, wv.w, z[3]);
            }
        }
    }

    size_t ci = ((size_t)b * HID + oc) * HW + (size_t)y * W + x;
    float cprev = (t == 0) ? 0.0f : cbuf[ci];
    float ig = sigmoid_(z[0]);
    float fg = sigmoid_(z[1]);
    float og = sigmoid_(z[2]);
    float gg = tanh_(z[3]);
    float cn = fg * cprev + ig * gg;
    cbuf[ci] = cn;
    hbuf[((size_t)(b * T + t) * HID + oc) * HW + (size_t)y * W + x] = og * tanh_(cn);
}

// ---------------------------------------------------------------------------
// BatchNorm stats / BN+ReLU+Pool / FC head (unchanged, measured fine)
// ---------------------------------------------------------------------------
__global__ void bn_stats(const float* __restrict__ hbuf, float* __restrict__ stats,
                         int BT, int C, int HW)
{
    int c = blockIdx.x;
    float s = 0.0f, s2 = 0.0f;
    for (int bt = blockIdx.y; bt < BT; bt += gridDim.y) {
        const float* p = hbuf + ((size_t)bt * C + c) * HW;
        for (int i = threadIdx.x; i < HW; i += blockDim.x) {
            float v = p[i];
            s += v;
            s2 += v * v;
        }
    }
    __shared__ float ssum[256];
    __shared__ float ssq[256];
    int tid = threadIdx.x;
    ssum[tid] = s; ssq[tid] = s2;
    __syncthreads();
    for (int off = 128; off > 0; off >>= 1) {
        if (tid < off) { ssum[tid] += ssum[tid + off]; ssq[tid] += ssq[tid + off]; }
        __syncthreads();
    }
    if (tid == 0) {
        atomicAdd(&stats[2 * c + 0], ssum[0]);
        atomicAdd(&stats[2 * c + 1], ssq[0]);
    }
}

__global__ void bn_relu_pool(const float* __restrict__ hbuf,
                             const float* __restrict__ stats,
                             const float* __restrict__ gamma,
                             const float* __restrict__ beta,
                             float* __restrict__ out,
                             int BT, int C, int H, int W, float invN)
{
    int Ho = H / 2, Wo = W / 2;
    int idx = blockIdx.x * blockDim.x + threadIdx.x;
    int total = BT * C * Ho * Wo;
    if (idx >= total) return;
    int xo = idx % Wo;
    int yo = (idx / Wo) % Ho;
    int c  = (idx / (Wo * Ho)) % C;
    int bt = idx / (C * Ho * Wo);

    float mean = stats[2 * c + 0] * invN;
    float var  = stats[2 * c + 1] * invN - mean * mean;
    float sc = gamma[c] * rsqrtf(var + 1e-5f);
    float sh = beta[c] - mean * sc;

    const float* p = hbuf + ((size_t)bt * C + c) * (H * W) + (2 * yo) * W + 2 * xo;
    float a0 = fmaxf(fmaf(p[0],     sc, sh), 0.0f);
    float a1 = fmaxf(fmaf(p[1],     sc, sh), 0.0f);
    float a2 = fmaxf(fmaf(p[W],     sc, sh), 0.0f);
    float a3 = fmaxf(fmaf(p[W + 1], sc, sh), 0.0f);
    out[idx] = fmaxf(fmaxf(a0, a1), fmaxf(a2, a3));
}

__global__ __launch_bounds__(128) void fc_head(const float* __restrict__ feat,
                                               const float* __restrict__ fc1w,
                                               const float* __restrict__ fc1b,
                                               const float* __restrict__ fc2w,
                                               const float* __restrict__ fc2b,
                                               float* __restrict__ out)
{
    __shared__ float sf[1024];
    __shared__ float y1[128];
    int bt = blockIdx.x;
    const float* f = feat + (size_t)bt * 1024;
    for (int i = threadIdx.x; i < 1024; i += 128) sf[i] = f[i];
    __syncthreads();
    int k = threadIdx.x;
    float acc = fc1b[k];
    const float* wk = fc1w + (size_t)k * 1024;
    for (int d = 0; d < 1024; ++d) acc = fmaf(sf[d], wk[d], acc);
    y1[k] = fmaxf(acc, 0.0f);
    __syncthreads();
    if (k < 2) {
        float a = fc2b[k];
        const float* w2 = fc2w + k * 128;
        for (int j = 0; j < 128; ++j) a = fmaf(y1[j], w2[j], a);
        out[(size_t)bt * 2 + k] = a;
    }
}

// ---------------------------------------------------------------------------
// Host
// ---------------------------------------------------------------------------
static void launch_zx(int l, const float* in, const float* w, const float* bias,
                      float* zbuf, int t0, int TcAct, int TcMax, int B, int T,
                      int Cin, int hid, int H, int W, hipStream_t s)
{
    int Ctot = Cin + hid;
    switch (l) {
        case 0: { // Cin=1: scalar weights fine. nOcg=4, BPP=8
            zx_k<256,4,2><<<B*TcAct*4*8, 256, 0, s>>>(
                in,w,bias,zbuf,t0,TcAct,TcMax,B,T,Cin,Ctot,hid,H,W,4,8); } break;
        case 1: { // LDS weights, nOcg=8, BPP=4
            zx_lds<256,4,16,1><<<B*TcAct*8*4, 256, 0, s>>>(
                in,w,bias,zbuf,t0,TcAct,TcMax,B,T,Ctot,hid,H,W,8,4,TcAct); } break;
        case 2: { // nOcg=16, BPP=1
            zx_lds<256,4,32,1><<<B*TcAct*16, 256, 0, s>>>(
                in,w,bias,zbuf,t0,TcAct,TcMax,B,T,Ctot,hid,H,W,16,1,TcAct); } break;
        case 3: { // nOcg=16, BPP=1, TCB=4
            int nTcb = (TcAct + 3) / 4;
            zx_lds<256,4,64,4><<<B*nTcb*16, 256, 0, s>>>(
                in,w,bias,zbuf,t0,TcAct,TcMax,B,T,Ctot,hid,H,W,16,1,nTcb); } break;
    }
}

static void launch_step(int l, const float* zbuf, const float* w,
                        float* hbuf, float* cbuf, int t, int tc, int TcMax,
                        int B, int T, int Cin, int hid, int H, int W, hipStream_t s)
{
    // OCB=4, TPO=64, px/block=64: blocks = B * (hid/4) * (H/ROWS_geom)
    switch (l) {
        case 0: // W=64 ROWS=1: nOcg=4,  BPP=64 -> 2048 blocks
            step_t<256,4,1,16,64,64><<<2048,256,0,s>>>(zbuf,w,hbuf,cbuf,t,tc,TcMax,B,T,Cin, 4,64); break;
        case 1: // W=32 ROWS=2: nOcg=8,  BPP=16 -> 1024 blocks
            step_t<256,4,2,32,32,32><<<1024,256,0,s>>>(zbuf,w,hbuf,cbuf,t,tc,TcMax,B,T,Cin, 8,16); break;
        case 2: // W=16 ROWS=4: nOcg=16, BPP=4  -> 512 blocks
            step_t<256,4,4,64,16,16><<< 512,256,0,s>>>(zbuf,w,hbuf,cbuf,t,tc,TcMax,B,T,Cin,16, 4); break;
        case 3: // W=8  ROWS=8: nOcg=16, BPP=1  -> 128 blocks
            step_t<256,4,8,64, 8, 8><<< 128,256,0,s>>>(zbuf,w,hbuf,cbuf,t,tc,TcMax,B,T,Cin,16, 1); break;
    }
}

extern "C" void kernel_launch(void* const* d_in, const int* in_sizes, int n_in,
                              void* d_out, int out_size, void* d_ws, size_t ws_size,
                              hipStream_t stream)
{
    const int B = 8, T = 40;
    const float* x = (const float*)d_in[0];

    // workspace layout (floats); ~141 MB total (proven available)
    float* hbuf  = (float*)d_ws;                 // 20,971,520
    float* pbuf  = hbuf + (size_t)20971520;      //  5,242,880
    float* cbuf  = pbuf + (size_t)5242880;       //    524,288
    float* stats = cbuf + (size_t)524288;        //        128
    float* zbuf  = stats + 128;                  //  8,388,608

    struct LCfg { int Cin, hid, H, W, Tc; };
    const LCfg L[4] = { {1, 16, 64, 64, 4}, {16, 32, 32, 32, 8},
                        {32, 64, 16, 16, 16}, {64, 64, 8, 8, 40} };

    const float* in = x;
    for (int l = 0; l < 4; ++l) {
        const float* w     = (const float*)d_in[1 + 4 * l];
        const float* bias  = (const float*)d_in[2 + 4 * l];
        const float* gamma = (const float*)d_in[3 + 4 * l];
        const float* beta  = (const float*)d_in[4 + 4 * l];
        const int Cin = L[l].Cin, hid = L[l].hid, H = L[l].H, W = L[l].W;
        const int HW = H * W;
        const int TcMax = L[l].Tc;

        for (int t0 = 0; t0 < T; t0 += TcMax) {
            int TcAct = (T - t0 < TcMax) ? (T - t0) : TcMax;
            launch_zx(l, in, w, bias, zbuf, t0, TcAct, TcMax, B, T, Cin, hid, H, W, stream);
            for (int t = t0; t < t0 + TcAct; ++t)
                launch_step(l, zbuf, w, hbuf, cbuf, t, t - t0, TcMax,
                            B, T, Cin, hid, H, W, stream);
        }

        hipMemsetAsync(stats, 0, 2 * hid * sizeof(float), stream);
        bn_stats<<<dim3(hid, 80), 256, 0, stream>>>(hbuf, stats, B * T, hid, HW);

        int ptotal = B * T * hid * (H / 2) * (W / 2);
        float invN = 1.0f / ((float)(B * T) * (float)HW);
        bn_relu_pool<<<(ptotal + 255) / 256, 256, 0, stream>>>(
            hbuf, stats, gamma, beta, pbuf, B * T, hid, H, W, invN);
        in = pbuf;
    }

    const float* fc1w = (const float*)d_in[17];
    const float* fc1b = (const float*)d_in[18];
    const float* fc2w = (const float*)d_in[19];
    const float* fc2b = (const float*)d_in[20];
    fc_head<<<B * T, 128, 0, stream>>>(pbuf, fc1w, fc1b, fc2w, fc2b, (float*)d_out);
}